// Round 1
// baseline (649.225 us; speedup 1.0000x reference)
//
#include <hip/hip_runtime.h>
#include <hip/hip_bf16.h>
#include <stdint.h>

#define B_SZ 32
#define S_SZ 2048
#define H_SZ 1024
#define K_SZ 1024
#define M_SZ (B_SZ * S_SZ)   // 65536 rows of the big GEMM

typedef __attribute__((ext_vector_type(8))) short bf16x8;   // 8 bf16 = 4 VGPRs (MFMA A/B frag)
typedef __attribute__((ext_vector_type(4))) float f32x4;    // MFMA C/D frag

// ---- helpers ----------------------------------------------------------------

__device__ __forceinline__ short f2bf_rne(float f) {
    uint32_t u = __builtin_bit_cast(uint32_t, f);
    u += 0x7fffu + ((u >> 16) & 1u);   // round-to-nearest-even
    return (short)(u >> 16);
}

__device__ __forceinline__ float fast_tanh(float x) {
    // tanh(x) = 1 - 2/(exp(2x)+1); exact limits at +-inf, ~1e-6 rel err.
    float ex = __expf(2.0f * x);
    return 1.0f - 2.0f / (ex + 1.0f);
}

// ---- fp32 -> bf16 conversion (8 elems/thread, grid-stride) ------------------

__global__ void cvt_bf16_k(const float* __restrict__ in,
                           __hip_bfloat16* __restrict__ out, int n8) {
    int idx = blockIdx.x * blockDim.x + threadIdx.x;
    int stride = gridDim.x * blockDim.x;
    for (int i = idx; i < n8; i += stride) {
        const float4* p = (const float4*)in + (size_t)i * 2;
        float4 a = p[0], b = p[1];
        bf16x8 r;
        r[0] = f2bf_rne(a.x); r[1] = f2bf_rne(a.y);
        r[2] = f2bf_rne(a.z); r[3] = f2bf_rne(a.w);
        r[4] = f2bf_rne(b.x); r[5] = f2bf_rne(b.y);
        r[6] = f2bf_rne(b.z); r[7] = f2bf_rne(b.w);
        ((bf16x8*)out)[i] = r;
    }
}

// ---- dec_proj[b][k] = dot(dec[b,:], Wb[k,:]) + Wb_b[k] + Wc_b[k] ------------
// one wave per output; coalesced float4 + shfl reduce

__global__ __launch_bounds__(256) void decproj_k(
    const float* __restrict__ ds, const float* __restrict__ Wb,
    const float* __restrict__ Wb_b, const float* __restrict__ Wc_b,
    float* __restrict__ dp) {
    int g = blockIdx.x * 4 + (threadIdx.x >> 6);   // wave id = output id
    int lane = threadIdx.x & 63;
    int b = g >> 10;
    int k = g & 1023;
    const float4* wrow = (const float4*)(Wb + (size_t)k * H_SZ);
    const float4* xrow = (const float4*)(ds + (size_t)b * H_SZ);
    float sum = 0.f;
#pragma unroll
    for (int it = 0; it < 4; it++) {
        float4 w = wrow[lane + it * 64];
        float4 x = xrow[lane + it * 64];
        sum += w.x * x.x + w.y * x.y + w.z * x.z + w.w * x.w;
    }
#pragma unroll
    for (int off = 1; off < 64; off <<= 1) sum += __shfl_xor(sum, off, 64);
    if (lane == 0) dp[g] = sum + Wb_b[k] + Wc_b[k];
}

// ---- big GEMM: C[m][n] = sum_h A[m][h] * Wc[n][h], fused epilogue ----------
// scores_part[slot][m] += over its 64 cols of Wa[n]*tanh(C[m][n]+decp[b][n])
// m97 structure: 128x128 tile, BK=32, 16x16x32 bf16 MFMA, global_load_lds w=16.
// AF32 variant stages fp32 A and converts in-register (ws-too-small fallback).

template <bool AF32>
__global__ __launch_bounds__(256) void gemm_scores_k(
    const void* __restrict__ Aptr, const __hip_bfloat16* __restrict__ Bw,
    const float* __restrict__ decp, const float* __restrict__ Wa,
    float* __restrict__ sp) {
    constexpr int ABYTES = AF32 ? 128 * 32 * 4 : 128 * 32 * 2;
    __shared__ __align__(16) unsigned char AsmRaw[ABYTES];
    __shared__ __align__(16) unsigned char BsmRaw[128 * 32 * 2];

    const int t = threadIdx.x;
    const int wave = t >> 6;
    const int lane = t & 63;
    const int wm = wave >> 1, wn = wave & 1;   // 2x2 waves over 128x128 tile
    const int quad = lane >> 4;
    const int l15 = lane & 15;

    const int colBlk = blockIdx.x & 7;    // k-fastest: 8 consecutive blocks share A tile (L2)
    const int rowBlk = blockIdx.x >> 3;
    const int row0 = rowBlk * 128;
    const int col0 = colBlk * 128;
    const int b = row0 >> 11;             // 128 | 2048 so tile is within one batch row

    f32x4 acc[4][4];
#pragma unroll
    for (int i = 0; i < 4; i++)
#pragma unroll
        for (int j = 0; j < 4; j++) acc[i][j] = f32x4{0.f, 0.f, 0.f, 0.f};

    const __hip_bfloat16* Ab = (const __hip_bfloat16*)Aptr;
    const float* Af = (const float*)Aptr;

    for (int k0 = 0; k0 < H_SZ; k0 += 32) {
        // -- stage A tile (global_load_lds, 16B/lane, LDS = uniform base + lane*16) --
        if constexpr (AF32) {
#pragma unroll
            for (int inst = 0; inst < 4; inst++) {
                int slot = inst * 256 + t;            // 16B slots; [128][32] f32 row-major
                int r = slot >> 3, c4 = slot & 7;
                const float* g = Af + (size_t)(row0 + r) * H_SZ + k0 + c4 * 4;
                __builtin_amdgcn_global_load_lds(
                    (const __attribute__((address_space(1))) void*)g,
                    (__attribute__((address_space(3))) void*)(AsmRaw + inst * 4096 + wave * 1024),
                    16, 0, 0);
            }
        } else {
#pragma unroll
            for (int inst = 0; inst < 2; inst++) {
                int slot = inst * 256 + t;            // [128][32] bf16 row-major
                int r = slot >> 2, c8 = slot & 3;
                const __hip_bfloat16* g = Ab + (size_t)(row0 + r) * H_SZ + k0 + c8 * 8;
                __builtin_amdgcn_global_load_lds(
                    (const __attribute__((address_space(1))) void*)g,
                    (__attribute__((address_space(3))) void*)(AsmRaw + inst * 4096 + wave * 1024),
                    16, 0, 0);
            }
        }
        // -- stage B tile (Wc is [N][H], contraction contiguous: NT layout) --
#pragma unroll
        for (int inst = 0; inst < 2; inst++) {
            int slot = inst * 256 + t;
            int r = slot >> 2, c8 = slot & 3;
            const __hip_bfloat16* g = Bw + (size_t)(col0 + r) * H_SZ + k0 + c8 * 8;
            __builtin_amdgcn_global_load_lds(
                (const __attribute__((address_space(1))) void*)g,
                (__attribute__((address_space(3))) void*)(BsmRaw + inst * 4096 + wave * 1024),
                16, 0, 0);
        }
        __syncthreads();   // drains vmcnt -> LDS ready

        // -- fragments: A[m=l15][k=quad*8+j], B[n=l15][k=quad*8+j] --
        bf16x8 afr[4], bfr[4];
#pragma unroll
        for (int i = 0; i < 4; i++) {
            int r = wm * 64 + i * 16 + l15;
            if constexpr (AF32) {
                const float* ap = (const float*)AsmRaw + r * 32 + quad * 8;
                f32x4 lo = *(const f32x4*)ap;
                f32x4 hi = *(const f32x4*)(ap + 4);
                bf16x8 v;
                v[0] = f2bf_rne(lo[0]); v[1] = f2bf_rne(lo[1]);
                v[2] = f2bf_rne(lo[2]); v[3] = f2bf_rne(lo[3]);
                v[4] = f2bf_rne(hi[0]); v[5] = f2bf_rne(hi[1]);
                v[6] = f2bf_rne(hi[2]); v[7] = f2bf_rne(hi[3]);
                afr[i] = v;
            } else {
                afr[i] = *(const bf16x8*)((const __hip_bfloat16*)AsmRaw + r * 32 + quad * 8);
            }
        }
#pragma unroll
        for (int j = 0; j < 4; j++) {
            int r = wn * 64 + j * 16 + l15;
            bfr[j] = *(const bf16x8*)((const __hip_bfloat16*)BsmRaw + r * 32 + quad * 8);
        }
#pragma unroll
        for (int i = 0; i < 4; i++)
#pragma unroll
            for (int j = 0; j < 4; j++)
                acc[i][j] = __builtin_amdgcn_mfma_f32_16x16x32_bf16(afr[i], bfr[j], acc[i][j], 0, 0, 0);
        __syncthreads();   // reads done before next stage overwrites
    }

    // -- fused epilogue: partial_m = sum_n Wa[n]*tanh(C[m][n]+decp[b][n]) --
    float wa_j[4], dp_j[4];
#pragma unroll
    for (int j = 0; j < 4; j++) {
        int c = col0 + wn * 64 + j * 16 + l15;
        wa_j[j] = Wa[c];
        dp_j[j] = decp[b * K_SZ + c];
    }
    const int slotIdx = colBlk * 2 + wn;   // 16 partial slots per row
#pragma unroll
    for (int i = 0; i < 4; i++) {
#pragma unroll
        for (int r = 0; r < 4; r++) {
            float tsum = 0.f;
#pragma unroll
            for (int j = 0; j < 4; j++)
                tsum += wa_j[j] * fast_tanh(acc[i][j][r] + dp_j[j]);
            // C/D layout: row=(lane>>4)*4+reg, col=lane&15 -> reduce over the 16 cols
#pragma unroll
            for (int off = 1; off < 16; off <<= 1) tsum += __shfl_xor(tsum, off, 64);
            if (l15 == 0) {
                int m = row0 + wm * 64 + i * 16 + quad * 4 + r;
                sp[(size_t)slotIdx * M_SZ + m] = tsum;
            }
        }
    }
}

// ---- softmax over S per batch row (reduces the 16 partial slots) -----------

__global__ __launch_bounds__(256) void softmax_k(
    const float* __restrict__ sp, float* __restrict__ attn) {
    int b = blockIdx.x;
    int t = threadIdx.x;
    __shared__ float wred[4];
    __shared__ float wred2[4];
    float sc[8];
    float mx = -1e30f;
#pragma unroll
    for (int u = 0; u < 8; u++) {
        int m = b * S_SZ + t + u * 256;
        float v = 0.f;
#pragma unroll
        for (int c = 0; c < 16; c++) v += sp[(size_t)c * M_SZ + m];
        sc[u] = v;
        mx = fmaxf(mx, v);
    }
#pragma unroll
    for (int off = 1; off < 64; off <<= 1) mx = fmaxf(mx, __shfl_xor(mx, off, 64));
    if ((t & 63) == 0) wred[t >> 6] = mx;
    __syncthreads();
    mx = fmaxf(fmaxf(wred[0], wred[1]), fmaxf(wred[2], wred[3]));
    float lsum = 0.f;
#pragma unroll
    for (int u = 0; u < 8; u++) { sc[u] = expf(sc[u] - mx); lsum += sc[u]; }
#pragma unroll
    for (int off = 1; off < 64; off <<= 1) lsum += __shfl_xor(lsum, off, 64);
    if ((t & 63) == 0) wred2[t >> 6] = lsum;
    __syncthreads();
    float inv = 1.f / (wred2[0] + wred2[1] + wred2[2] + wred2[3]);
#pragma unroll
    for (int u = 0; u < 8; u++) attn[b * S_SZ + t + u * 256] = sc[u] * inv;
}

// ---- context partials: cp[c][b][h] = sum_{s in chunk c} attn[b,s]*enc[b,s,h]

__global__ __launch_bounds__(256) void ctx_part_k(
    const float* __restrict__ attn, const float* __restrict__ enc,
    float* __restrict__ cp) {
    int b = blockIdx.x >> 4;
    int c = blockIdx.x & 15;
    int t = threadIdx.x;
    __shared__ float wloc[128];
    if (t < 128) wloc[t] = attn[b * S_SZ + c * 128 + t];
    __syncthreads();
    const float4* ep = (const float4*)(enc + ((size_t)b * S_SZ + (size_t)c * 128) * H_SZ);
    float4 acc = {0.f, 0.f, 0.f, 0.f};
    for (int s = 0; s < 128; s++) {
        float w = wloc[s];
        float4 v = ep[s * 256 + t];
        acc.x += w * v.x; acc.y += w * v.y; acc.z += w * v.z; acc.w += w * v.w;
    }
    ((float4*)(cp + ((size_t)c * B_SZ + b) * H_SZ))[t] = acc;
}

__global__ void ctx_red_k(const float* __restrict__ cp, float* __restrict__ out) {
    int i = blockIdx.x * blockDim.x + threadIdx.x;   // 0..32767
    float s = 0.f;
#pragma unroll
    for (int c = 0; c < 16; c++) s += cp[(size_t)c * (B_SZ * H_SZ) + i];
    out[i] = s;
}

// ---- launch -----------------------------------------------------------------

extern "C" void kernel_launch(void* const* d_in, const int* in_sizes, int n_in,
                              void* d_out, int out_size, void* d_ws, size_t ws_size,
                              hipStream_t stream) {
    const float* dec  = (const float*)d_in[0];
    const float* enc  = (const float*)d_in[1];
    const float* Wa_w = (const float*)d_in[2];
    // d_in[3] = Wa_b: softmax is shift-invariant, scalar bias cancels exactly.
    const float* Wb_w = (const float*)d_in[4];
    const float* Wb_b = (const float*)d_in[5];
    const float* Wc_w = (const float*)d_in[6];
    const float* Wc_b = (const float*)d_in[7];
    float* out = (float*)d_out;

    char* ws = (char*)d_ws;
    size_t off = 0;
    auto alloc = [&](size_t bytes) -> void* {
        void* p = ws + off;
        off += (bytes + 255) & ~(size_t)255;
        return p;
    };
    __hip_bfloat16* wc_bf = (__hip_bfloat16*)alloc((size_t)K_SZ * H_SZ * 2);
    float* dp     = (float*)alloc((size_t)B_SZ * K_SZ * 4);
    float* spart  = (float*)alloc((size_t)16 * M_SZ * 4);
    float* attn   = (float*)alloc((size_t)B_SZ * S_SZ * 4);
    float* cpart  = (float*)alloc((size_t)16 * B_SZ * H_SZ * 4);
    __hip_bfloat16* enc_bf = (__hip_bfloat16*)alloc((size_t)M_SZ * H_SZ * 2);
    const bool useBf16A = (off <= ws_size);   // ws_size-dependent only: same every call

    cvt_bf16_k<<<512, 256, 0, stream>>>(Wc_w, wc_bf, K_SZ * H_SZ / 8);
    if (useBf16A)
        cvt_bf16_k<<<8192, 256, 0, stream>>>(enc, enc_bf, M_SZ * H_SZ / 8);
    decproj_k<<<8192, 256, 0, stream>>>(dec, Wb_w, Wb_b, Wc_b, dp);
    if (useBf16A)
        gemm_scores_k<false><<<(M_SZ / 128) * 8, 256, 0, stream>>>(enc_bf, wc_bf, dp, Wa_w, spart);
    else
        gemm_scores_k<true><<<(M_SZ / 128) * 8, 256, 0, stream>>>(enc, wc_bf, dp, Wa_w, spart);
    softmax_k<<<B_SZ, 256, 0, stream>>>(spart, attn);
    ctx_part_k<<<B_SZ * 16, 256, 0, stream>>>(attn, enc, cpart);
    ctx_red_k<<<128, 256, 0, stream>>>(cpart, out);
}

// Round 2
// 613.537 us; speedup vs baseline: 1.0582x; 1.0582x over previous
//
#include <hip/hip_runtime.h>
#include <hip/hip_bf16.h>
#include <stdint.h>

#define B_SZ 32
#define S_SZ 2048
#define H_SZ 1024
#define K_SZ 1024
#define M_SZ (B_SZ * S_SZ)   // 65536 rows of the big GEMM

typedef __attribute__((ext_vector_type(8))) short bf16x8;   // 8 bf16 = 4 VGPRs (MFMA A/B frag)
typedef __attribute__((ext_vector_type(4))) float f32x4;    // MFMA C/D frag

// ---- helpers ----------------------------------------------------------------

__device__ __forceinline__ short f2bf_rne(float f) {
    uint32_t u = __builtin_bit_cast(uint32_t, f);
    u += 0x7fffu + ((u >> 16) & 1u);   // round-to-nearest-even
    return (short)(u >> 16);
}

__device__ __forceinline__ float bf2f(unsigned short u) {
    return __builtin_bit_cast(float, (uint32_t)u << 16);
}

__device__ __forceinline__ float fast_tanh(float x) {
    // tanh(x) = 1 - 2/(exp(2x)+1); exact limits at +-inf, ~1e-6 rel err.
    float ex = __expf(2.0f * x);
    return 1.0f - 2.0f / (ex + 1.0f);
}

// ---- fp32 -> bf16 conversion (8 elems/thread, grid-stride) ------------------

__global__ void cvt_bf16_k(const float* __restrict__ in,
                           __hip_bfloat16* __restrict__ out, int n8) {
    int idx = blockIdx.x * blockDim.x + threadIdx.x;
    int stride = gridDim.x * blockDim.x;
    for (int i = idx; i < n8; i += stride) {
        const float4* p = (const float4*)in + (size_t)i * 2;
        float4 a = p[0], b = p[1];
        bf16x8 r;
        r[0] = f2bf_rne(a.x); r[1] = f2bf_rne(a.y);
        r[2] = f2bf_rne(a.z); r[3] = f2bf_rne(a.w);
        r[4] = f2bf_rne(b.x); r[5] = f2bf_rne(b.y);
        r[6] = f2bf_rne(b.z); r[7] = f2bf_rne(b.w);
        ((bf16x8*)out)[i] = r;
    }
}

// ---- dec_proj[b][k] = dot(dec[b,:], Wb[k,:]) + Wb_b[k] + Wc_b[k] ------------
// one wave per output; coalesced float4 + shfl reduce

__global__ __launch_bounds__(256) void decproj_k(
    const float* __restrict__ ds, const float* __restrict__ Wb,
    const float* __restrict__ Wb_b, const float* __restrict__ Wc_b,
    float* __restrict__ dp) {
    int g = blockIdx.x * 4 + (threadIdx.x >> 6);   // wave id = output id
    int lane = threadIdx.x & 63;
    int b = g >> 10;
    int k = g & 1023;
    const float4* wrow = (const float4*)(Wb + (size_t)k * H_SZ);
    const float4* xrow = (const float4*)(ds + (size_t)b * H_SZ);
    float sum = 0.f;
#pragma unroll
    for (int it = 0; it < 4; it++) {
        float4 w = wrow[lane + it * 64];
        float4 x = xrow[lane + it * 64];
        sum += w.x * x.x + w.y * x.y + w.z * x.z + w.w * x.w;
    }
#pragma unroll
    for (int off = 1; off < 64; off <<= 1) sum += __shfl_xor(sum, off, 64);
    if (lane == 0) dp[g] = sum + Wb_b[k] + Wc_b[k];
}

// ---- big GEMM: C[m][n] = sum_h A[m][h] * Wc[n][h], fused epilogue ----------
// scores_part[slot][m] += over its 64 cols of Wa[n]*tanh(C[m][n]+decp[b][n])
// m97 structure: 128x128 tile, BK=32, 16x16x32 bf16 MFMA, global_load_lds w=16.
// Block swizzle: all 8 colBlks of a rowBlk get ids == (r&7) mod 8 -> same XCD
// (round-robin id%8 -> XCD) at consecutive per-XCD slots, so the A tile is
// fetched into that XCD's L2 once instead of 8 times.
// AF32 variant stages fp32 A and converts in-register (ws-too-small fallback).

template <bool AF32>
__global__ __launch_bounds__(256) void gemm_scores_k(
    const void* __restrict__ Aptr, const __hip_bfloat16* __restrict__ Bw,
    const float* __restrict__ decp, const float* __restrict__ Wa,
    float* __restrict__ sp) {
    constexpr int ABYTES = AF32 ? 128 * 32 * 4 : 128 * 32 * 2;
    __shared__ __align__(16) unsigned char AsmRaw[ABYTES];
    __shared__ __align__(16) unsigned char BsmRaw[128 * 32 * 2];

    const int t = threadIdx.x;
    const int wave = t >> 6;
    const int lane = t & 63;
    const int wm = wave >> 1, wn = wave & 1;   // 2x2 waves over 128x128 tile
    const int quad = lane >> 4;
    const int l15 = lane & 15;

    const int id = blockIdx.x;
    const int colBlk = (id >> 3) & 7;
    const int rowBlk = ((id >> 6) << 3) | (id & 7);
    const int row0 = rowBlk * 128;
    const int col0 = colBlk * 128;
    const int b = row0 >> 11;             // 128 | 2048 so tile is within one batch row

    f32x4 acc[4][4];
#pragma unroll
    for (int i = 0; i < 4; i++)
#pragma unroll
        for (int j = 0; j < 4; j++) acc[i][j] = f32x4{0.f, 0.f, 0.f, 0.f};

    const __hip_bfloat16* Ab = (const __hip_bfloat16*)Aptr;
    const float* Af = (const float*)Aptr;

    for (int k0 = 0; k0 < H_SZ; k0 += 32) {
        // -- stage A tile (global_load_lds, 16B/lane, LDS = uniform base + lane*16) --
        if constexpr (AF32) {
#pragma unroll
            for (int inst = 0; inst < 4; inst++) {
                int slot = inst * 256 + t;            // 16B slots; [128][32] f32 row-major
                int r = slot >> 3, c4 = slot & 7;
                const float* g = Af + (size_t)(row0 + r) * H_SZ + k0 + c4 * 4;
                __builtin_amdgcn_global_load_lds(
                    (const __attribute__((address_space(1))) void*)g,
                    (__attribute__((address_space(3))) void*)(AsmRaw + inst * 4096 + wave * 1024),
                    16, 0, 0);
            }
        } else {
#pragma unroll
            for (int inst = 0; inst < 2; inst++) {
                int slot = inst * 256 + t;            // [128][32] bf16 row-major
                int r = slot >> 2, c8 = slot & 3;
                const __hip_bfloat16* g = Ab + (size_t)(row0 + r) * H_SZ + k0 + c8 * 8;
                __builtin_amdgcn_global_load_lds(
                    (const __attribute__((address_space(1))) void*)g,
                    (__attribute__((address_space(3))) void*)(AsmRaw + inst * 4096 + wave * 1024),
                    16, 0, 0);
            }
        }
        // -- stage B tile (Wc is [N][H], contraction contiguous: NT layout) --
#pragma unroll
        for (int inst = 0; inst < 2; inst++) {
            int slot = inst * 256 + t;
            int r = slot >> 2, c8 = slot & 3;
            const __hip_bfloat16* g = Bw + (size_t)(col0 + r) * H_SZ + k0 + c8 * 8;
            __builtin_amdgcn_global_load_lds(
                (const __attribute__((address_space(1))) void*)g,
                (__attribute__((address_space(3))) void*)(BsmRaw + inst * 4096 + wave * 1024),
                16, 0, 0);
        }
        __syncthreads();   // drains vmcnt -> LDS ready

        // -- fragments: A[m=l15][k=quad*8+j], B[n=l15][k=quad*8+j] --
        bf16x8 afr[4], bfr[4];
#pragma unroll
        for (int i = 0; i < 4; i++) {
            int r = wm * 64 + i * 16 + l15;
            if constexpr (AF32) {
                const float* ap = (const float*)AsmRaw + r * 32 + quad * 8;
                f32x4 lo = *(const f32x4*)ap;
                f32x4 hi = *(const f32x4*)(ap + 4);
                bf16x8 v;
                v[0] = f2bf_rne(lo[0]); v[1] = f2bf_rne(lo[1]);
                v[2] = f2bf_rne(lo[2]); v[3] = f2bf_rne(lo[3]);
                v[4] = f2bf_rne(hi[0]); v[5] = f2bf_rne(hi[1]);
                v[6] = f2bf_rne(hi[2]); v[7] = f2bf_rne(hi[3]);
                afr[i] = v;
            } else {
                afr[i] = *(const bf16x8*)((const __hip_bfloat16*)AsmRaw + r * 32 + quad * 8);
            }
        }
#pragma unroll
        for (int j = 0; j < 4; j++) {
            int r = wn * 64 + j * 16 + l15;
            bfr[j] = *(const bf16x8*)((const __hip_bfloat16*)BsmRaw + r * 32 + quad * 8);
        }
#pragma unroll
        for (int i = 0; i < 4; i++)
#pragma unroll
            for (int j = 0; j < 4; j++)
                acc[i][j] = __builtin_amdgcn_mfma_f32_16x16x32_bf16(afr[i], bfr[j], acc[i][j], 0, 0, 0);
        __syncthreads();   // reads done before next stage overwrites
    }

    // -- fused epilogue: partial_m = sum_n Wa[n]*tanh(C[m][n]+decp[b][n]) --
    float wa_j[4], dp_j[4];
#pragma unroll
    for (int j = 0; j < 4; j++) {
        int c = col0 + wn * 64 + j * 16 + l15;
        wa_j[j] = Wa[c];
        dp_j[j] = decp[b * K_SZ + c];
    }
    const int slotIdx = colBlk * 2 + wn;   // 16 partial slots per row
#pragma unroll
    for (int i = 0; i < 4; i++) {
#pragma unroll
        for (int r = 0; r < 4; r++) {
            float tsum = 0.f;
#pragma unroll
            for (int j = 0; j < 4; j++)
                tsum += wa_j[j] * fast_tanh(acc[i][j][r] + dp_j[j]);
            // C/D layout: row=(lane>>4)*4+reg, col=lane&15 -> reduce over the 16 cols
#pragma unroll
            for (int off = 1; off < 16; off <<= 1) tsum += __shfl_xor(tsum, off, 64);
            if (l15 == 0) {
                int m = row0 + wm * 64 + i * 16 + quad * 4 + r;
                sp[(size_t)slotIdx * M_SZ + m] = tsum;
            }
        }
    }
}

// ---- softmax over S per batch row (reduces the 16 partial slots) -----------

__global__ __launch_bounds__(256) void softmax_k(
    const float* __restrict__ sp, float* __restrict__ attn) {
    int b = blockIdx.x;
    int t = threadIdx.x;
    __shared__ float wred[4];
    __shared__ float wred2[4];
    float sc[8];
    float mx = -1e30f;
#pragma unroll
    for (int u = 0; u < 8; u++) {
        int m = b * S_SZ + t + u * 256;
        float v = 0.f;
#pragma unroll
        for (int c = 0; c < 16; c++) v += sp[(size_t)c * M_SZ + m];
        sc[u] = v;
        mx = fmaxf(mx, v);
    }
#pragma unroll
    for (int off = 1; off < 64; off <<= 1) mx = fmaxf(mx, __shfl_xor(mx, off, 64));
    if ((t & 63) == 0) wred[t >> 6] = mx;
    __syncthreads();
    mx = fmaxf(fmaxf(wred[0], wred[1]), fmaxf(wred[2], wred[3]));
    float lsum = 0.f;
#pragma unroll
    for (int u = 0; u < 8; u++) { sc[u] = expf(sc[u] - mx); lsum += sc[u]; }
#pragma unroll
    for (int off = 1; off < 64; off <<= 1) lsum += __shfl_xor(lsum, off, 64);
    if ((t & 63) == 0) wred2[t >> 6] = lsum;
    __syncthreads();
    float inv = 1.f / (wred2[0] + wred2[1] + wred2[2] + wred2[3]);
#pragma unroll
    for (int u = 0; u < 8; u++) attn[b * S_SZ + t + u * 256] = sc[u] * inv;
}

// ---- context partials: cp[c][b][h] = sum_{s in chunk c} attn[b,s]*enc[b,s,h]
// 32 chunks of 64 seq positions -> 1024 blocks. BF16E reads the bf16 copy.

template <bool BF16E>
__global__ __launch_bounds__(256) void ctx_part_k(
    const float* __restrict__ attn, const void* __restrict__ encp,
    float* __restrict__ cp) {
    int b = blockIdx.x >> 5;
    int c = blockIdx.x & 31;
    int t = threadIdx.x;
    __shared__ float wloc[64];
    if (t < 64) wloc[t] = attn[b * S_SZ + c * 64 + t];
    __syncthreads();
    float4 acc = {0.f, 0.f, 0.f, 0.f};
    if constexpr (BF16E) {
        const ushort4* ep = (const ushort4*)((const __hip_bfloat16*)encp +
                              ((size_t)b * S_SZ + (size_t)c * 64) * H_SZ);
#pragma unroll 8
        for (int s = 0; s < 64; s++) {
            float w = wloc[s];
            ushort4 v = ep[s * 256 + t];
            acc.x += w * bf2f(v.x); acc.y += w * bf2f(v.y);
            acc.z += w * bf2f(v.z); acc.w += w * bf2f(v.w);
        }
    } else {
        const float4* ep = (const float4*)((const float*)encp +
                              ((size_t)b * S_SZ + (size_t)c * 64) * H_SZ);
#pragma unroll 8
        for (int s = 0; s < 64; s++) {
            float w = wloc[s];
            float4 v = ep[s * 256 + t];
            acc.x += w * v.x; acc.y += w * v.y;
            acc.z += w * v.z; acc.w += w * v.w;
        }
    }
    ((float4*)(cp + ((size_t)c * B_SZ + b) * H_SZ))[t] = acc;
}

__global__ void ctx_red_k(const float* __restrict__ cp, float* __restrict__ out) {
    int i = blockIdx.x * blockDim.x + threadIdx.x;   // 0..32767
    float s = 0.f;
#pragma unroll
    for (int c = 0; c < 32; c++) s += cp[(size_t)c * (B_SZ * H_SZ) + i];
    out[i] = s;
}

// ---- launch -----------------------------------------------------------------

extern "C" void kernel_launch(void* const* d_in, const int* in_sizes, int n_in,
                              void* d_out, int out_size, void* d_ws, size_t ws_size,
                              hipStream_t stream) {
    const float* dec  = (const float*)d_in[0];
    const float* enc  = (const float*)d_in[1];
    const float* Wa_w = (const float*)d_in[2];
    // d_in[3] = Wa_b: softmax is shift-invariant, scalar bias cancels exactly.
    const float* Wb_w = (const float*)d_in[4];
    const float* Wb_b = (const float*)d_in[5];
    const float* Wc_w = (const float*)d_in[6];
    const float* Wc_b = (const float*)d_in[7];
    float* out = (float*)d_out;

    char* ws = (char*)d_ws;
    size_t off = 0;
    auto alloc = [&](size_t bytes) -> void* {
        void* p = ws + off;
        off += (bytes + 255) & ~(size_t)255;
        return p;
    };
    __hip_bfloat16* wc_bf = (__hip_bfloat16*)alloc((size_t)K_SZ * H_SZ * 2);
    float* dp     = (float*)alloc((size_t)B_SZ * K_SZ * 4);
    float* spart  = (float*)alloc((size_t)16 * M_SZ * 4);
    float* attn   = (float*)alloc((size_t)B_SZ * S_SZ * 4);
    float* cpart  = (float*)alloc((size_t)32 * B_SZ * H_SZ * 4);
    __hip_bfloat16* enc_bf = (__hip_bfloat16*)alloc((size_t)M_SZ * H_SZ * 2);
    const bool useBf16A = (off <= ws_size);   // ws_size-dependent only: same every call

    cvt_bf16_k<<<512, 256, 0, stream>>>(Wc_w, wc_bf, K_SZ * H_SZ / 8);
    if (useBf16A)
        cvt_bf16_k<<<8192, 256, 0, stream>>>(enc, enc_bf, M_SZ * H_SZ / 8);
    decproj_k<<<8192, 256, 0, stream>>>(dec, Wb_w, Wb_b, Wc_b, dp);
    if (useBf16A)
        gemm_scores_k<false><<<(M_SZ / 128) * 8, 256, 0, stream>>>(enc_bf, wc_bf, dp, Wa_w, spart);
    else
        gemm_scores_k<true><<<(M_SZ / 128) * 8, 256, 0, stream>>>(enc, wc_bf, dp, Wa_w, spart);
    softmax_k<<<B_SZ, 256, 0, stream>>>(spart, attn);
    if (useBf16A)
        ctx_part_k<true><<<B_SZ * 32, 256, 0, stream>>>(attn, enc_bf, cpart);
    else
        ctx_part_k<false><<<B_SZ * 32, 256, 0, stream>>>(attn, enc, cpart);
    ctx_red_k<<<128, 256, 0, stream>>>(cpart, out);
}